// Round 1
// baseline (129.536 us; speedup 1.0000x reference)
//
#include <hip/hip_runtime.h>

// CombinedLoss: 0.99 * dice + 0.01 * mean(phi * sigmoid(pred))
// phi = signed exact EDT of targets mask (16 x 512 x 512), clip |phi|>1e5 -> 0.
//
// ws layout:
//   [0, 8388608)            : u16 g[16][512][512]   (1D row-distance field, one mask at a time)
//   [8388608, 8650752)      : double partials[2][4096][4]
// total ~8.65 MB

#define NPIX (16 * 512 * 512)   // 4194304 = 2^22
#define NB2  4096               // pass-2 blocks
#define SENTINEL 65535.0f

// ---------------------------------------------------------------------------
// Pass 1: exact 1D distance along width per row, via min-plus prefix scans.
// One wave (64 lanes) per row, 8 elements per lane. m=0: sites = (t==0),
// m=1: sites = (t!=0). Output u16, 65535 = "no site in row" sentinel.
// ---------------------------------------------------------------------------
__global__ __launch_bounds__(256) void edt_rows(const int* __restrict__ t,
                                                unsigned short* __restrict__ g,
                                                int m) {
    const int wave = threadIdx.x >> 6;
    const int lane = threadIdx.x & 63;
    const int row  = (blockIdx.x << 2) + wave;   // 0..8191 (16 images * 512 rows)
    const int base = row << 9;                   // * 512
    const int x0   = lane << 3;                  // 8 elems / lane

    const int4* tp = (const int4*)(t + base + x0);
    int4 ta = tp[0], tb = tp[1];
    int tv[8] = {ta.x, ta.y, ta.z, ta.w, tb.x, tb.y, tb.z, tb.w};

    float pen[8];
#pragma unroll
    for (int i = 0; i < 8; ++i) {
        bool site = m ? (tv[i] != 0) : (tv[i] == 0);
        pen[i] = site ? 0.0f : 1.0e6f;
    }

    const float BIG = 3.0e37f;

    // forward: f[x] = x + cummin(pen - x)
    float pf[8];
    float run = BIG;
#pragma unroll
    for (int i = 0; i < 8; ++i) { run = fminf(run, pen[i] - (float)(x0 + i)); pf[i] = run; }
    float incl = run;
#pragma unroll
    for (int off = 1; off < 64; off <<= 1) {
        float u = __shfl_up(incl, (unsigned)off, 64);
        if (lane >= off) incl = fminf(incl, u);
    }
    float excl = __shfl_up(incl, 1u, 64);
    if (lane == 0) excl = BIG;

    // backward: b[x] = -x + rev-cummin(pen + x)
    float sf[8];
    run = BIG;
#pragma unroll
    for (int i = 7; i >= 0; --i) { run = fminf(run, pen[i] + (float)(x0 + i)); sf[i] = run; }
    float inclb = run;
#pragma unroll
    for (int off = 1; off < 64; off <<= 1) {
        float u = __shfl_down(inclb, (unsigned)off, 64);
        if (lane + off < 64) inclb = fminf(inclb, u);
    }
    float exclb = __shfl_down(inclb, 1u, 64);
    if (lane == 63) exclb = BIG;

    // g = min(fwd, bwd), clamp to u16 (real g <= 511; >=512 means "no site")
    unsigned int pk[4];
#pragma unroll
    for (int i = 0; i < 8; i += 2) {
        float xa = (float)(x0 + i);
        float fa = xa + fminf(pf[i], excl);
        float ba = -xa + fminf(sf[i], exclb);
        float ga = fminf(fminf(fa, ba), SENTINEL);
        float xb = (float)(x0 + i + 1);
        float fb = xb + fminf(pf[i + 1], excl);
        float bb = -xb + fminf(sf[i + 1], exclb);
        float gb = fminf(fminf(fb, bb), SENTINEL);
        pk[i >> 1] = (unsigned int)ga | ((unsigned int)gb << 16);
    }
    uint4 outv = {pk[0], pk[1], pk[2], pk[3]};
    *((uint4*)(g + base + x0)) = outv;
}

// ---------------------------------------------------------------------------
// Pass 2: d2[y][x] = min_y' (g[y'][x]^2 + (y-y')^2), via symmetric outward
// scan with early exit (k^2 >= current min => no further improvement).
// Fused: sigmoid, phi clip, and the four loss reductions.
// m=0: accumulate at fg pixels (phi = -d_in), also sum p, p*t, t.
// m=1: accumulate at bg pixels (phi = +d_out), also sum p.
// ---------------------------------------------------------------------------
__global__ __launch_bounds__(256) void edt_cols_loss(const int* __restrict__ t,
                                                     const float* __restrict__ pred,
                                                     const unsigned short* __restrict__ g,
                                                     double* __restrict__ partials,
                                                     int m) {
    double s_b = 0.0, s_p = 0.0, s_i = 0.0;
    int s_t = 0;

    for (int idx = blockIdx.x * 256 + threadIdx.x; idx < NPIX; idx += NB2 * 256) {
        int tv = t[idx];
        bool active = m ? (tv == 0) : (tv != 0);
        if (!active) continue;

        int x = idx & 511;
        int y = (idx >> 9) & 511;
        int n = idx >> 18;

        float p = 1.0f / (1.0f + expf(-pred[idx]));

        const unsigned short* gc = g + (n << 18) + x;   // column, stride 512
        float gv = (float)gc[y << 9];
        if (gv >= SENTINEL) gv = 1.0e6f;
        float m2 = gv * gv;

        for (int k = 1; k < 512; ++k) {
            float k2 = (float)(k * k);
            if (k2 >= m2) break;
            int yd = y - k;
            if (yd >= 0) {
                float gg = (float)gc[yd << 9];
                if (gg >= SENTINEL) gg = 1.0e6f;
                m2 = fminf(m2, fmaf(gg, gg, k2));
            }
            int yu = y + k;
            if (yu < 512) {
                float gg = (float)gc[yu << 9];
                if (gg >= SENTINEL) gg = 1.0e6f;
                m2 = fminf(m2, fmaf(gg, gg, k2));
            }
        }

        float d = sqrtf(m2);
        float phi = m ? d : -d;
        if (d > 100000.0f) phi = 0.0f;   // reference: |phi|>1e5 -> 0 (covers empty-class case)

        s_b += (double)(phi * p);
        s_p += (double)p;
        if (!m) { s_i += (double)p; s_t += 1; }
    }

    __shared__ double red[256][4];
    red[threadIdx.x][0] = s_b;
    red[threadIdx.x][1] = s_p;
    red[threadIdx.x][2] = s_i;
    red[threadIdx.x][3] = (double)s_t;
    __syncthreads();
    for (int s = 128; s > 0; s >>= 1) {
        if (threadIdx.x < s) {
            red[threadIdx.x][0] += red[threadIdx.x + s][0];
            red[threadIdx.x][1] += red[threadIdx.x + s][1];
            red[threadIdx.x][2] += red[threadIdx.x + s][2];
            red[threadIdx.x][3] += red[threadIdx.x + s][3];
        }
        __syncthreads();
    }
    if (threadIdx.x == 0) {
        double* dst = partials + (size_t)blockIdx.x * 4;
        dst[0] = red[0][0];
        dst[1] = red[0][1];
        dst[2] = red[0][2];
        dst[3] = red[0][3];
    }
}

// ---------------------------------------------------------------------------
// Final: reduce 2*NB2 partial rows, compute loss scalar.
// ---------------------------------------------------------------------------
__global__ __launch_bounds__(256) void finalize_loss(const double* __restrict__ partials,
                                                     float* __restrict__ out) {
    __shared__ double red[256][4];
    double s0 = 0.0, s1 = 0.0, s2 = 0.0, s3 = 0.0;
    for (int i = threadIdx.x; i < 2 * NB2; i += 256) {
        const double* src = partials + (size_t)i * 4;
        s0 += src[0]; s1 += src[1]; s2 += src[2]; s3 += src[3];
    }
    red[threadIdx.x][0] = s0;
    red[threadIdx.x][1] = s1;
    red[threadIdx.x][2] = s2;
    red[threadIdx.x][3] = s3;
    __syncthreads();
    for (int s = 128; s > 0; s >>= 1) {
        if (threadIdx.x < s) {
            red[threadIdx.x][0] += red[threadIdx.x + s][0];
            red[threadIdx.x][1] += red[threadIdx.x + s][1];
            red[threadIdx.x][2] += red[threadIdx.x + s][2];
            red[threadIdx.x][3] += red[threadIdx.x + s][3];
        }
        __syncthreads();
    }
    if (threadIdx.x == 0) {
        double sb = red[0][0];   // sum(phi * p)
        double sp = red[0][1];   // sum(p)
        double si = red[0][2];   // sum(p * t)
        double st = red[0][3];   // sum(t)
        double dice = 1.0 - (2.0 * si + 1e-6) / (sp + st + 1e-6);
        double boundary = sb / (double)NPIX;
        out[0] = (float)(0.99 * dice + 0.01 * boundary);
    }
}

extern "C" void kernel_launch(void* const* d_in, const int* in_sizes, int n_in,
                              void* d_out, int out_size, void* d_ws, size_t ws_size,
                              hipStream_t stream) {
    const float* pred = (const float*)d_in[0];
    const int*   targ = (const int*)d_in[1];
    unsigned short* g = (unsigned short*)d_ws;
    double* partials = (double*)((char*)d_ws + (size_t)NPIX * 2);  // +8388608 B
    float* out = (float*)d_out;

    for (int m = 0; m < 2; ++m) {
        edt_rows<<<2048, 256, 0, stream>>>(targ, g, m);
        edt_cols_loss<<<NB2, 256, 0, stream>>>(targ, pred, g,
                                               partials + (size_t)m * NB2 * 4, m);
    }
    finalize_loss<<<1, 256, 0, stream>>>(partials, out);
}

// Round 2
// 98.925 us; speedup vs baseline: 1.3094x; 1.3094x over previous
//
#include <hip/hip_runtime.h>

// CombinedLoss: 0.99 * dice + 0.01 * mean(phi * sigmoid(pred))
// phi = signed exact EDT of targets mask (16 x 512 x 512), clip |phi|>1e5 -> 0.
//
// Round 2 structure (3 dispatches, was 5):
//   k1 edt_rows_both : one read of t -> BOTH 1D row-distance fields (u16) + bit-packed mask
//   k2 edt_cols_loss : every pixel once; field select = per-lane base pointer; fused loss sums
//   k3 finalize
//
// ws layout:
//   [0,        8388608)  u16 g0[16][512][512]  (sites = background, used by fg pixels)
//   [8388608, 16777216)  u16 g1[16][512][512]  (sites = foreground, used by bg pixels)
//   [16777216,17301504)  mask bits, 1 = foreground, bit i of word idx>>5
//   [17301504,17432576)  double partials[4096][4]

#define NPIX (16 * 512 * 512)   // 4194304
#define NB2  4096               // pass-2 blocks (NPIX / (256*4))
#define SENT 65535.0f

// ---------------------------------------------------------------------------
// k1: exact 1D distance along width per row for BOTH site sets.
// One wave per row, 8 elems/lane. g in [0,511] or 65535 (= "no site in row").
// Also writes the bit-packed foreground mask (byte per lane, 64 B per row).
// ---------------------------------------------------------------------------
__global__ __launch_bounds__(256) void edt_rows_both(const int* __restrict__ t,
                                                     unsigned short* __restrict__ g,
                                                     unsigned char* __restrict__ mb) {
    const int wave = threadIdx.x >> 6;
    const int lane = threadIdx.x & 63;
    const int row  = (blockIdx.x << 2) + wave;   // 0..8191
    const int base = row << 9;
    const int x0   = lane << 3;

    const int4* tp = (const int4*)(t + base + x0);
    int4 ta = tp[0], tb = tp[1];
    int tv[8] = {ta.x, ta.y, ta.z, ta.w, tb.x, tb.y, tb.z, tb.w};

    float pen[2][8];
    unsigned int mybyte = 0;
#pragma unroll
    for (int i = 0; i < 8; ++i) {
        bool fg = (tv[i] != 0);
        pen[0][i] = fg ? 1.0e6f : 0.0f;   // sites = background
        pen[1][i] = fg ? 0.0f : 1.0e6f;   // sites = foreground
        mybyte |= (fg ? 1u : 0u) << i;
    }
    mb[(row << 6) + lane] = (unsigned char)mybyte;

    const float BIG = 3.0e37f;

#pragma unroll
    for (int f = 0; f < 2; ++f) {
        // forward: fwd[x] = x + cummin(pen - x)
        float pf[8];
        float run = BIG;
#pragma unroll
        for (int i = 0; i < 8; ++i) { run = fminf(run, pen[f][i] - (float)(x0 + i)); pf[i] = run; }
        float incl = run;
#pragma unroll
        for (int off = 1; off < 64; off <<= 1) {
            float u = __shfl_up(incl, (unsigned)off, 64);
            if (lane >= off) incl = fminf(incl, u);
        }
        float excl = __shfl_up(incl, 1u, 64);
        if (lane == 0) excl = BIG;

        // backward: bwd[x] = -x + rev-cummin(pen + x)
        float sf[8];
        run = BIG;
#pragma unroll
        for (int i = 7; i >= 0; --i) { run = fminf(run, pen[f][i] + (float)(x0 + i)); sf[i] = run; }
        float inclb = run;
#pragma unroll
        for (int off = 1; off < 64; off <<= 1) {
            float u = __shfl_down(inclb, (unsigned)off, 64);
            if (lane + off < 64) inclb = fminf(inclb, u);
        }
        float exclb = __shfl_down(inclb, 1u, 64);
        if (lane == 63) exclb = BIG;

        unsigned int pk[4];
#pragma unroll
        for (int i = 0; i < 8; i += 2) {
            float xa = (float)(x0 + i);
            float fa = xa + fminf(pf[i], excl);
            float ba = -xa + fminf(sf[i], exclb);
            float ga = fminf(fminf(fa, ba), SENT);
            float xb = (float)(x0 + i + 1);
            float fb = xb + fminf(pf[i + 1], excl);
            float bb = -xb + fminf(sf[i + 1], exclb);
            float gb = fminf(fminf(fb, bb), SENT);
            pk[i >> 1] = (unsigned int)ga | ((unsigned int)gb << 16);
        }
        uint4 outv = {pk[0], pk[1], pk[2], pk[3]};
        *((uint4*)(g + (size_t)f * NPIX + base + x0)) = outv;
    }
}

// ---------------------------------------------------------------------------
// k2: per pixel, d2 = min_y' (gsel[y'][x]^2 + (y-y')^2) via symmetric outward
// scan with early exit. 4 consecutive pixels per thread, interleaved scan.
// Sentinel rows need no remap: 65535^2 = 4.3e9 always loses to any real
// candidate (<= 5.3e5); if it wins, d = 65535 -> the d > 1e4 clip gives
// phi = 0, exactly matching the reference's |phi| > 1e5 -> 0 (INF = 1e6).
// Fused: sigmoid + all four loss sums (boundary, sum p, sum p*t, sum t).
// ---------------------------------------------------------------------------
__global__ __launch_bounds__(256) void edt_cols_loss(const float* __restrict__ pred,
                                                     const unsigned short* __restrict__ g,
                                                     const unsigned int* __restrict__ mw,
                                                     double* __restrict__ partials) {
    const int tid  = blockIdx.x * 256 + threadIdx.x;
    const int idx0 = tid << 2;                 // 4 consecutive pixels
    const int n    = idx0 >> 18;
    const int y    = (idx0 >> 9) & 511;
    const int x    = idx0 & 511;               // x..x+3 within the row

    const unsigned int bits = (mw[idx0 >> 5] >> (idx0 & 31)) & 0xF;

    const float4 p4 = *((const float4*)(pred + idx0));
    float pv[4] = {p4.x, p4.y, p4.z, p4.w};

    const ushort4 g0v = *((const ushort4*)(g + idx0));
    const ushort4 g1v = *((const ushort4*)(g + NPIX + idx0));
    const unsigned short g0a[4] = {g0v.x, g0v.y, g0v.z, g0v.w};
    const unsigned short g1a[4] = {g1v.x, g1v.y, g1v.z, g1v.w};

    const unsigned short* gcv[4];
    float m2[4];
    float mx = 0.0f;
#pragma unroll
    for (int j = 0; j < 4; ++j) {
        bool fg = (bits >> j) & 1;
        float gv = (float)(fg ? g0a[j] : g1a[j]);
        m2[j] = gv * gv;
        mx = fmaxf(mx, m2[j]);
        gcv[j] = g + (fg ? 0 : NPIX) + (n << 18) + x + j;   // column base, stride 512
    }

    for (int k = 1; k < 512; ++k) {
        float k2 = (float)(k * k);
        if (k2 >= mx) break;
        int yd = y - k;
        int yu = y + k;
        mx = 0.0f;
#pragma unroll
        for (int j = 0; j < 4; ++j) {
            if (k2 < m2[j]) {
                if (yd >= 0) {
                    float gg = (float)gcv[j][yd << 9];
                    m2[j] = fminf(m2[j], fmaf(gg, gg, k2));
                }
                if (yu < 512) {
                    float gg = (float)gcv[j][yu << 9];
                    m2[j] = fminf(m2[j], fmaf(gg, gg, k2));
                }
            }
            mx = fmaxf(mx, m2[j]);
        }
    }

    double s_b = 0.0, s_p = 0.0, s_i = 0.0;
    int s_t = 0;
#pragma unroll
    for (int j = 0; j < 4; ++j) {
        bool fg = (bits >> j) & 1;
        float p = 1.0f / (1.0f + expf(-pv[j]));
        float d = sqrtf(m2[j]);
        float phi = fg ? -d : d;
        if (d > 1.0e4f) phi = 0.0f;   // only sentinel-derived d (>= 65535) lands here
        s_b += (double)(phi * p);
        s_p += (double)p;
        if (fg) { s_i += (double)p; s_t += 1; }
    }
    double s_tt = (double)s_t;

    // wave butterfly reduce (64 lanes), then cross-wave via tiny LDS
#pragma unroll
    for (int off = 32; off > 0; off >>= 1) {
        s_b  += __shfl_xor(s_b,  off, 64);
        s_p  += __shfl_xor(s_p,  off, 64);
        s_i  += __shfl_xor(s_i,  off, 64);
        s_tt += __shfl_xor(s_tt, off, 64);
    }
    __shared__ double sred[4][4];
    const int wave = threadIdx.x >> 6;
    const int lane = threadIdx.x & 63;
    if (lane == 0) {
        sred[wave][0] = s_b; sred[wave][1] = s_p; sred[wave][2] = s_i; sred[wave][3] = s_tt;
    }
    __syncthreads();
    if (threadIdx.x == 0) {
        double* dst = partials + (size_t)blockIdx.x * 4;
#pragma unroll
        for (int c = 0; c < 4; ++c)
            dst[c] = sred[0][c] + sred[1][c] + sred[2][c] + sred[3][c];
    }
}

// ---------------------------------------------------------------------------
// k3: reduce 4096 partial rows, emit loss scalar.
// ---------------------------------------------------------------------------
__global__ __launch_bounds__(256) void finalize_loss(const double* __restrict__ partials,
                                                     float* __restrict__ out) {
    __shared__ double red[256][4];
    double s0 = 0.0, s1 = 0.0, s2 = 0.0, s3 = 0.0;
    for (int i = threadIdx.x; i < NB2; i += 256) {
        const double* src = partials + (size_t)i * 4;
        s0 += src[0]; s1 += src[1]; s2 += src[2]; s3 += src[3];
    }
    red[threadIdx.x][0] = s0;
    red[threadIdx.x][1] = s1;
    red[threadIdx.x][2] = s2;
    red[threadIdx.x][3] = s3;
    __syncthreads();
    for (int s = 128; s > 0; s >>= 1) {
        if (threadIdx.x < s) {
            red[threadIdx.x][0] += red[threadIdx.x + s][0];
            red[threadIdx.x][1] += red[threadIdx.x + s][1];
            red[threadIdx.x][2] += red[threadIdx.x + s][2];
            red[threadIdx.x][3] += red[threadIdx.x + s][3];
        }
        __syncthreads();
    }
    if (threadIdx.x == 0) {
        double sb = red[0][0];   // sum(phi * p)
        double sp = red[0][1];   // sum(p)
        double si = red[0][2];   // sum(p * t)
        double st = red[0][3];   // sum(t)
        double dice = 1.0 - (2.0 * si + 1e-6) / (sp + st + 1e-6);
        double boundary = sb / (double)NPIX;
        out[0] = (float)(0.99 * dice + 0.01 * boundary);
    }
}

extern "C" void kernel_launch(void* const* d_in, const int* in_sizes, int n_in,
                              void* d_out, int out_size, void* d_ws, size_t ws_size,
                              hipStream_t stream) {
    const float* pred = (const float*)d_in[0];
    const int*   targ = (const int*)d_in[1];
    unsigned short* gfield = (unsigned short*)d_ws;
    unsigned char*  mbytes = (unsigned char*)d_ws + (size_t)NPIX * 4;          // 16777216
    double* partials = (double*)((char*)d_ws + (size_t)NPIX * 4 + NPIX / 8);   // 17301504
    float* out = (float*)d_out;

    edt_rows_both<<<2048, 256, 0, stream>>>(targ, gfield, mbytes);
    edt_cols_loss<<<NB2, 256, 0, stream>>>(pred, gfield, (const unsigned int*)mbytes, partials);
    finalize_loss<<<1, 256, 0, stream>>>(partials, out);
}

// Round 3
// 94.831 us; speedup vs baseline: 1.3660x; 1.0432x over previous
//
#include <hip/hip_runtime.h>

// CombinedLoss: 0.99 * dice + 0.01 * mean(phi * sigmoid(pred))
// phi = signed exact EDT of targets mask (16 x 512 x 512), |phi|>1e5 -> 0.
//
// Round 3: single fused EDT kernel. Each block owns a 32-row slab of one
// image and computes the 1D row-distance fields for slab+16-row halo into
// LDS (u32 = g0 | g1<<16 per pixel, 64x512x4 = 128 KB), then runs the
// column lower-envelope scan + loss sums entirely from LDS. A pixel whose
// distance isn't resolved within the halo (needs k>16, never happens on
// Bernoulli(0.5) data) takes an exact global-t fallback, so the kernel is
// exact for ANY input.
//
// ws: double partials[256][4] at offset 0 (fully rewritten every call).

#define HH 512
#define WW 512
#define BH 32      // output rows per block
#define HALO 16
#define TR 64      // LDS tile rows
#define NT 512     // threads per block
#define NBLK 256   // 16 images * 16 slabs
#define SENT 65535.0f

// exact per-pixel fallback: full-image search with pruning (ultra-rare path)
__device__ float fallback_exact(const int* __restrict__ t, int n, int y, int x,
                                bool fg, float m2) {
    const int* tn = t + (n << 18);
    for (int yy = 0; yy < HH; ++yy) {
        float dy = (float)(yy - y);
        float dy2 = dy * dy;
        if (dy2 >= m2) continue;
        const int* row = tn + (yy << 9);
        int lim = (int)sqrtf(m2 - dy2);
        for (int dx = 0; dx <= lim; ++dx) {
            bool hit = false;
            int xl = x - dx, xr = x + dx;
            if (xl >= 0) { int v = row[xl]; hit = fg ? (v == 0) : (v != 0); }
            if (!hit && xr < WW) { int v = row[xr]; hit = fg ? (v == 0) : (v != 0); }
            if (hit) {
                float c = fmaf((float)dx, (float)dx, dy2);
                if (c < m2) m2 = c;
                break;
            }
        }
    }
    return m2;
}

__global__ __launch_bounds__(NT, 1) void edt_fused(const int* __restrict__ t,
                                                   const float* __restrict__ pred,
                                                   double* __restrict__ partials) {
    __shared__ unsigned int gl[TR][WW];   // 128 KB: lo16 = g0 (sites=bg), hi16 = g1 (sites=fg)
    __shared__ double sred[8][4];

    const int n     = blockIdx.x >> 4;
    const int y0    = (blockIdx.x & 15) << 5;
    const int rbase = y0 - HALO;
    const int wave  = threadIdx.x >> 6;   // 0..7
    const int lane  = threadIdx.x & 63;
    const int x0    = lane << 3;
    const float BIG = 3.0e37f;

    // ---------------- phase 1: 1D row scans (both fields) into LDS ----------------
    for (int rr = wave; rr < TR; rr += 8) {
        const int gy = rbase + rr;
        if (gy < 0 || gy >= HH) {
            uint4 s = {0xFFFFFFFFu, 0xFFFFFFFFu, 0xFFFFFFFFu, 0xFFFFFFFFu};
            *((uint4*)&gl[rr][x0])     = s;
            *((uint4*)&gl[rr][x0 + 4]) = s;
            continue;
        }
        const int4* tp = (const int4*)(t + (n << 18) + (gy << 9) + x0);
        int4 ta = tp[0], tb = tp[1];
        int tv[8] = {ta.x, ta.y, ta.z, ta.w, tb.x, tb.y, tb.z, tb.w};

        float pen[2][8];
#pragma unroll
        for (int i = 0; i < 8; ++i) {
            bool fg = (tv[i] != 0);
            pen[0][i] = fg ? 1.0e6f : 0.0f;   // sites = background
            pen[1][i] = fg ? 0.0f : 1.0e6f;   // sites = foreground
        }

        unsigned short gout[2][8];
#pragma unroll
        for (int f = 0; f < 2; ++f) {
            float pf[8];
            float run = BIG;
#pragma unroll
            for (int i = 0; i < 8; ++i) { run = fminf(run, pen[f][i] - (float)(x0 + i)); pf[i] = run; }
            float incl = run;
#pragma unroll
            for (int off = 1; off < 64; off <<= 1) {
                float u = __shfl_up(incl, (unsigned)off, 64);
                if (lane >= off) incl = fminf(incl, u);
            }
            float excl = __shfl_up(incl, 1u, 64);
            if (lane == 0) excl = BIG;

            float sf[8];
            run = BIG;
#pragma unroll
            for (int i = 7; i >= 0; --i) { run = fminf(run, pen[f][i] + (float)(x0 + i)); sf[i] = run; }
            float inclb = run;
#pragma unroll
            for (int off = 1; off < 64; off <<= 1) {
                float u = __shfl_down(inclb, (unsigned)off, 64);
                if (lane + off < 64) inclb = fminf(inclb, u);
            }
            float exclb = __shfl_down(inclb, 1u, 64);
            if (lane == 63) exclb = BIG;

#pragma unroll
            for (int i = 0; i < 8; ++i) {
                float xa = (float)(x0 + i);
                float fa = xa + fminf(pf[i], excl);
                float ba = -xa + fminf(sf[i], exclb);
                gout[f][i] = (unsigned short)fminf(fminf(fa, ba), SENT);
            }
        }

        unsigned int pk[8];
#pragma unroll
        for (int i = 0; i < 8; ++i)
            pk[i] = (unsigned int)gout[0][i] | ((unsigned int)gout[1][i] << 16);
        uint4 o0 = {pk[0], pk[1], pk[2], pk[3]};
        uint4 o1 = {pk[4], pk[5], pk[6], pk[7]};
        *((uint4*)&gl[rr][x0])     = o0;
        *((uint4*)&gl[rr][x0 + 4]) = o1;
    }
    __syncthreads();

    // ---------------- phase 2: column scan + fused loss sums ----------------
    double s_b = 0.0, s_p = 0.0, s_i = 0.0;
    int s_t = 0;

#pragma unroll 1
    for (int grp = 0; grp < 8; ++grp) {
        const int pid = (grp * NT + threadIdx.x) << 2;   // 0..16383, 4 consecutive px
        const int yl  = pid >> 9;                        // 0..31
        const int x   = pid & 511;
        const int r   = yl + HALO;                       // 16..47 -> r-16 >= 0, r+16 <= 63

        const float4 p4 = *((const float4*)(pred + (n << 18) + ((y0 + yl) << 9) + x));
        const float pv[4] = {p4.x, p4.y, p4.z, p4.w};

        const uint4 ow = *((const uint4*)&gl[r][x]);
        const unsigned int w[4] = {ow.x, ow.y, ow.z, ow.w};

        bool  fg[4];
        float m2[4];
        float mx = 0.0f;
#pragma unroll
        for (int j = 0; j < 4; ++j) {
            unsigned int lo = w[j] & 0xFFFFu, hi = w[j] >> 16;
            fg[j] = (hi == 0u);
            float gv = (float)(fg[j] ? lo : hi);
            m2[j] = gv * gv;
            mx = fmaxf(mx, m2[j]);
        }

        for (int k = 1; k <= HALO; ++k) {
            float k2 = (float)(k * k);
            if (k2 >= mx) break;
            const uint4 wd4 = *((const uint4*)&gl[r - k][x]);
            const uint4 wu4 = *((const uint4*)&gl[r + k][x]);
            const unsigned int wd[4] = {wd4.x, wd4.y, wd4.z, wd4.w};
            const unsigned int wu[4] = {wu4.x, wu4.y, wu4.z, wu4.w};
            mx = 0.0f;
#pragma unroll
            for (int j = 0; j < 4; ++j) {
                if (k2 < m2[j]) {
                    unsigned int a = fg[j] ? (wd[j] & 0xFFFFu) : (wd[j] >> 16);
                    unsigned int b = fg[j] ? (wu[j] & 0xFFFFu) : (wu[j] >> 16);
                    float fa = (float)a, fb = (float)b;
                    m2[j] = fminf(m2[j], fminf(fmaf(fa, fa, k2), fmaf(fb, fb, k2)));
                }
                mx = fmaxf(mx, m2[j]);
            }
        }

        if (mx > 289.0f) {   // some pixel unresolved past halo (never on random data)
#pragma unroll
            for (int j = 0; j < 4; ++j)
                if (m2[j] > 289.0f)
                    m2[j] = fallback_exact(t, n, y0 + yl, x + j, fg[j], m2[j]);
        }

#pragma unroll
        for (int j = 0; j < 4; ++j) {
            float p = 1.0f / (1.0f + expf(-pv[j]));
            float d = sqrtf(m2[j]);
            float phi = fg[j] ? -d : d;
            if (d > 1.0e4f) phi = 0.0f;   // sentinel-derived only; matches |phi|>1e5 -> 0
            s_b += (double)(phi * p);
            s_p += (double)p;
            if (fg[j]) { s_i += (double)p; s_t += 1; }
        }
    }
    double s_tt = (double)s_t;

    // ---------------- block reduce ----------------
#pragma unroll
    for (int off = 32; off > 0; off >>= 1) {
        s_b  += __shfl_xor(s_b,  off, 64);
        s_p  += __shfl_xor(s_p,  off, 64);
        s_i  += __shfl_xor(s_i,  off, 64);
        s_tt += __shfl_xor(s_tt, off, 64);
    }
    if (lane == 0) {
        sred[wave][0] = s_b; sred[wave][1] = s_p; sred[wave][2] = s_i; sred[wave][3] = s_tt;
    }
    __syncthreads();
    if (threadIdx.x == 0) {
        double* dst = partials + (size_t)blockIdx.x * 4;
#pragma unroll
        for (int c = 0; c < 4; ++c) {
            double acc = 0.0;
#pragma unroll
            for (int wv = 0; wv < 8; ++wv) acc += sred[wv][c];
            dst[c] = acc;
        }
    }
}

// ---------------- finalize: 256 partial rows -> loss scalar ----------------
__global__ __launch_bounds__(256) void finalize_loss(const double* __restrict__ partials,
                                                     float* __restrict__ out) {
    const int wave = threadIdx.x >> 6;
    const int lane = threadIdx.x & 63;
    const double* src = partials + (size_t)threadIdx.x * 4;
    double s0 = src[0], s1 = src[1], s2 = src[2], s3 = src[3];
#pragma unroll
    for (int off = 32; off > 0; off >>= 1) {
        s0 += __shfl_xor(s0, off, 64);
        s1 += __shfl_xor(s1, off, 64);
        s2 += __shfl_xor(s2, off, 64);
        s3 += __shfl_xor(s3, off, 64);
    }
    __shared__ double red[4][4];
    if (lane == 0) { red[wave][0] = s0; red[wave][1] = s1; red[wave][2] = s2; red[wave][3] = s3; }
    __syncthreads();
    if (threadIdx.x == 0) {
        double sb = red[0][0] + red[1][0] + red[2][0] + red[3][0];
        double sp = red[0][1] + red[1][1] + red[2][1] + red[3][1];
        double si = red[0][2] + red[1][2] + red[2][2] + red[3][2];
        double st = red[0][3] + red[1][3] + red[2][3] + red[3][3];
        double dice = 1.0 - (2.0 * si + 1e-6) / (sp + st + 1e-6);
        double boundary = sb / (double)(16 * 512 * 512);
        out[0] = (float)(0.99 * dice + 0.01 * boundary);
    }
}

extern "C" void kernel_launch(void* const* d_in, const int* in_sizes, int n_in,
                              void* d_out, int out_size, void* d_ws, size_t ws_size,
                              hipStream_t stream) {
    const float* pred = (const float*)d_in[0];
    const int*   targ = (const int*)d_in[1];
    double* partials = (double*)d_ws;        // 256 * 4 doubles, fully rewritten
    float* out = (float*)d_out;

    edt_fused<<<NBLK, NT, 0, stream>>>(targ, pred, partials);
    finalize_loss<<<1, 256, 0, stream>>>(partials, out);
}